// Round 8
// baseline (1505.220 us; speedup 1.0000x reference)
//
#include <hip/hip_runtime.h>
#include <hip/hip_fp16.h>

// ScalingAndSquaring: v <- v + warp(v), 7 steps, (2,3,160,160,160) f32.
// out(d,h,w) = v(d,h,w) + trilinear v(z~w, y~h, x~d)  (self-transposed gather).
// Round 8: rounds 1-7 proved the wall is the scattered gather-request stream
// (L2 line-request path, ~invariant across structures/bytes). Eliminate it:
// each block owns a 16^3 out-box and stages the <=26^3 halo'd source box
// (displacement bound |disp| <= 3.0 + 0.51 -> halo 5 safe) into LDS once,
// coalesced; all interpolation reads become LDS corner-pair reads.
// f32 LDS box 75.8 KB, 3 channel phases, 2 blocks/CU. fp16 intermediates.

constexpr int SZ  = 160;
constexpr int HW  = SZ * SZ;          // 25600
constexpr int DHW = SZ * SZ * SZ;     // 4096000
constexpr size_t HALFVOL = (size_t)2 * 3 * DHW * sizeof(__half); // 49,152,000 B

constexpr int LXS = 27;               // LDS x-stride (dwords), odd -> bank spread
constexpr int LZS = 27 * 27;          // LDS z-stride (729, odd)

typedef float vfloat2 __attribute__((ext_vector_type(2)));

template <typename TIN, typename TOUT>
__global__ __launch_bounds__(256, 2)
void warp_step(const TIN* __restrict__ src, TOUT* __restrict__ dst,
               float inScale)
{
    // 2000 blocks: XCD-contiguous swizzle (2000 % 8 == 0, bijective)
    const int wg = (int)blockIdx.x;
    const int r  = (wg & 7) * 250 + (wg >> 3);
    const int bw  = r % 10;                   // fastest: w-neighbors adjacent
    const int bh  = (r / 10) % 10;
    const int bd  = (r / 100) % 10;
    const int bat = r / 1000;
    const int d0 = bd * 16, h0 = bh * 16, w0 = bw * 16;

    const TIN* __restrict__ vb = src + (size_t)bat * 3 * DHW;
    TOUT*      __restrict__ db = dst + (size_t)bat * 3 * DHW;

    // staged source window: zz(D-axis)~w0, yy(H-axis)~h0, xx(W-axis)~d0
    const int zlo = max(w0 - 5, 0), zhi = min(w0 + 21, SZ), ez = zhi - zlo;
    const int ylo = max(h0 - 5, 0), yhi = min(h0 + 21, SZ), ey = yhi - ylo;
    const int xlo = max(d0 - 4, 0) & ~1;      // even (d0 is a multiple of 16)
    const int xhi = min(xlo + 26, SZ), ex = xhi - xlo;

    __shared__ float B[26 * LZS];             // 75,816 B -> 2 blocks/CU

    const int tid = (int)threadIdx.x;
    const int lw = tid & 15, lh = tid >> 4;   // sampling: (w,h) in-tile coords
    const size_t ohw = (size_t)(h0 + lh) * SZ + (w0 + lw);

    // ---- staging: coalesced rows (zz,yy) x 26 halves; 16 u32-lanes/row ----
    auto stage = [&](int ch) {
        const int j  = tid & 15;
        const int x2 = xlo + 2 * j;
        const bool xok = (j < 13) && (x2 < xhi);
        #pragma unroll 4
        for (int k = 0; k < 43; ++k) {
            const int rr = (tid >> 4) + k * 16;       // row id 0..675
            if (rr < 676 && xok) {
                const int lz = rr / 26;
                const int ly = rr - lz * 26;
                if (lz < ez && ly < ey) {
                    const size_t g = (size_t)ch * DHW
                                   + (size_t)(zlo + lz) * HW
                                   + (size_t)(ylo + ly) * SZ + x2;
                    float f0, f1;
                    if constexpr (sizeof(TIN) == 4) {
                        const vfloat2 vv =
                            *reinterpret_cast<const vfloat2*>(vb + g);
                        f0 = vv.x * inScale; f1 = vv.y * inScale;
                    } else {
                        const unsigned int u =
                            *reinterpret_cast<const unsigned int*>(vb + g);
                        f0 = __half2float(__ushort_as_half(
                                 (unsigned short)(u & 0xffffu))) * inScale;
                        f1 = __half2float(__ushort_as_half(
                                 (unsigned short)(u >> 16))) * inScale;
                    }
                    const int lb = lz * LZS + ly * LXS + 2 * j;
                    B[lb]     = f0;
                    B[lb + 1] = f1;
                }
            }
        }
    };

    // ---- precompute coords/addresses once (overlaps stage(0) latency) ----
    stage(0);

    int a00[16]; unsigned int pD[16];
    float wxa[16], wya[16], wza[16];
    {
        const float gyf = (float)(h0 + lh);
        const float gzf = (float)(w0 + lw);
        #pragma unroll
        for (int ld = 0; ld < 16; ++ld) {
            const size_t base = (size_t)(d0 + ld) * HW + ohw;
            float v0, v1, v2;
            if constexpr (sizeof(TIN) == 4) {
                v0 = vb[base] * inScale;
                v1 = vb[base + DHW] * inScale;
                v2 = vb[base + (size_t)2 * DHW] * inScale;
            } else {
                v0 = __half2float(vb[base]) * inScale;
                v1 = __half2float(vb[base + DHW]) * inScale;
                v2 = __half2float(vb[base + (size_t)2 * DHW]) * inScale;
            }
            // reference op sequence (validated through round 7)
            float ix = ((2.0f * (((float)(d0 + ld) + v0) / 159.0f - 0.5f) + 1.0f) * 160.0f - 1.0f) * 0.5f;
            float iy = ((2.0f * ((gyf + v1) / 159.0f - 0.5f) + 1.0f) * 160.0f - 1.0f) * 0.5f;
            float iz = ((2.0f * ((gzf + v2) / 159.0f - 0.5f) + 1.0f) * 160.0f - 1.0f) * 0.5f;
            ix = fminf(fmaxf(ix, 0.0f), 159.0f);
            iy = fminf(fmaxf(iy, 0.0f), 159.0f);
            iz = fminf(fmaxf(iz, 0.0f), 159.0f);
            const float fy = floorf(iy), fz = floorf(iz);
            const int x0 = (int)floorf(ix);
            const int y0 = (int)fy, z0 = (int)fz;
            const int y1 = min(y0 + 1, SZ - 1);
            const int z1 = min(z0 + 1, SZ - 1);
            // corner-pair: xp=min(x0,158), wx'=ix-xp (wx'==1 selects high at border)
            const int xp = min(x0, SZ - 2);
            wxa[ld] = ix - (float)xp;
            wya[ld] = iy - fy;
            wza[ld] = iz - fz;
            // local LDS indices (clamps are pure insurance; bounds proven)
            const int lx  = min(max(xp - xlo, 0), ex - 2);
            const int ly0 = min(max(y0 - ylo, 0), ey - 1);
            const int ly1 = min(max(y1 - ylo, 0), ey - 1);
            const int lz0 = min(max(z0 - zlo, 0), ez - 1);
            const int lz1 = min(max(z1 - zlo, 0), ez - 1);
            a00[ld] = lz0 * LZS + ly0 * LXS + lx;
            pD[ld]  = (unsigned int)((ly1 - ly0) * LXS)
                    | ((unsigned int)((lz1 - lz0) * LZS) << 16);
        }
    }

    // ---- sampling: 4 LDS corner-pair reads per voxel, all in-LDS ----
    auto sample = [&](int ch) {
        #pragma unroll
        for (int ld = 0; ld < 16; ++ld) {
            const int a  = a00[ld];
            const int dy = (int)(pD[ld] & 0xffffu);
            const int dz = (int)(pD[ld] >> 16);
            const float wx = wxa[ld], wy = wya[ld], wz = wza[ld];
            const float q00 = B[a],           q00h = B[a + 1];
            const float q01 = B[a + dy],      q01h = B[a + dy + 1];
            const float q10 = B[a + dz],      q10h = B[a + dz + 1];
            const float q11 = B[a + dy + dz], q11h = B[a + dy + dz + 1];
            const float s00 = q00 + wx * (q00h - q00);
            const float s01 = q01 + wx * (q01h - q01);
            const float s10 = q10 + wx * (q10h - q10);
            const float s11 = q11 + wx * (q11h - q11);
            const float wy0 = 1.0f - wy, wz0 = 1.0f - wz;
            const float res = (s00 * (wz0 * wy0) + s01 * (wz0 * wy))
                            + (s10 * (wz * wy0) + s11 * (wz * wy));
            const size_t off = (size_t)ch * DHW + (size_t)(d0 + ld) * HW + ohw;
            float own;
            if constexpr (sizeof(TIN) == 4) own = vb[off] * inScale;
            else own = __half2float(vb[off]) * inScale;
            const float o = own + res;      // B pre-scaled -> res already scaled
            if constexpr (sizeof(TOUT) == 4) db[off] = o;
            else db[off] = __float2half(o);
        }
    };

    __syncthreads();
    sample(0);
    __syncthreads();
    stage(1);
    __syncthreads();
    sample(1);
    __syncthreads();
    stage(2);
    __syncthreads();
    sample(2);
}

extern "C" void kernel_launch(void* const* d_in, const int* in_sizes, int n_in,
                              void* d_out, int out_size, void* d_ws, size_t ws_size,
                              hipStream_t stream)
{
    const float* vin = (const float*)d_in[0];
    float* out = (float*)d_out;
    __half* A = (__half*)d_ws;                       // fp16 volume 0
    __half* Bv = (__half*)((char*)d_ws + HALFVOL);   // fp16 volume 1
    // ws needs 2 * 49,152,000 B = 98,304,000 B.

    dim3 grid(2000), block(256);
    warp_step<float,  __half><<<grid, block, 0, stream>>>(vin, A, 1.0f / 128.0f); // v1
    warp_step<__half, __half><<<grid, block, 0, stream>>>(A, Bv, 1.0f);           // v2
    warp_step<__half, __half><<<grid, block, 0, stream>>>(Bv, A, 1.0f);           // v3
    warp_step<__half, __half><<<grid, block, 0, stream>>>(A, Bv, 1.0f);           // v4
    warp_step<__half, __half><<<grid, block, 0, stream>>>(Bv, A, 1.0f);           // v5
    warp_step<__half, __half><<<grid, block, 0, stream>>>(A, Bv, 1.0f);           // v6
    warp_step<__half, float ><<<grid, block, 0, stream>>>(Bv, out, 1.0f);         // v7
}